// Round 2
// baseline (237.680 us; speedup 1.0000x reference)
//
#include <hip/hip_runtime.h>

#define BB 4
#define SS 2
#define DD 16
#define CH 32          // S*D
#define PP (512*512)   // pixels per item
#define NSEGC 64
#define MARGINF 0.25f
#define BLK 256
#define PIXPT 4                 // pixels per thread (one int4 / one float4)
#define CHUNK (BLK*PIXPT)       // 1024 pixels per block
#define NCHUNK (PP/CHUNK)       // 256 chunks per batch -> grid 1024

// ---------------- kernel A: segment sums + counts ----------------
__global__ __launch_bounds__(BLK) void k_sums(const float* __restrict__ preds,
                                              const int* __restrict__ labels,
                                              float* __restrict__ g_sums,    // [B][CH][NSEG]
                                              float* __restrict__ g_counts)  // [B][NSEG]
{
    __shared__ float bins[CH * NSEGC];   // [ch][seg]
    __shared__ float cbins[NSEGC];
    const int b    = blockIdx.x / NCHUNK;
    const int base = (blockIdx.x % NCHUNK) * CHUNK;
    const int tid  = threadIdx.x;

    for (int i = tid; i < CH * NSEGC; i += BLK) bins[i] = 0.f;
    if (tid < NSEGC) cbins[tid] = 0.f;

    const int4 lv = ((const int4*)(labels + (size_t)b * PP + base))[tid];
    __syncthreads();

    atomicAdd(&cbins[lv.x], 1.f);
    atomicAdd(&cbins[lv.y], 1.f);
    atomicAdd(&cbins[lv.z], 1.f);
    atomicAdd(&cbins[lv.w], 1.f);

    const float* pb = preds + (size_t)b * CH * PP + base;
#pragma unroll 8
    for (int ch = 0; ch < CH; ++ch) {
        const float4 v = ((const float4*)(pb + (size_t)ch * PP))[tid];
        atomicAdd(&bins[ch * NSEGC + lv.x], v.x);
        atomicAdd(&bins[ch * NSEGC + lv.y], v.y);
        atomicAdd(&bins[ch * NSEGC + lv.z], v.z);
        atomicAdd(&bins[ch * NSEGC + lv.w], v.w);
    }
    __syncthreads();

    for (int i = tid; i < CH * NSEGC; i += BLK)
        atomicAdd(&g_sums[(size_t)b * CH * NSEGC + i], bins[i]);
    if (tid < NSEGC)
        atomicAdd(&g_counts[b * NSEGC + tid], cbins[tid]);
}

// ---------------- kernel B: centroids + push loss ----------------
__global__ __launch_bounds__(256) void k_push(const float* __restrict__ g_sums,
                                              const float* __restrict__ g_counts,
                                              float* __restrict__ g_cent,   // [B][NSEG][CH]
                                              float* __restrict__ g_push)   // [B]
{
    __shared__ float centB[CH * NSEGC];  // [ch][seg]
    __shared__ float red[4];
    const int b = blockIdx.x;
    const int tid = threadIdx.x;

    for (int i = tid; i < CH * NSEGC; i += 256) {
        const int ch = i >> 6, seg = i & 63;
        const float cnt = fmaxf(g_counts[b * NSEGC + seg], 1.0f);
        const float c = g_sums[(size_t)b * CH * NSEGC + i] / cnt;
        centB[i] = c;
        g_cent[(size_t)b * NSEGC * CH + seg * CH + ch] = c;
    }
    __syncthreads();

    float acc = 0.f;
    for (int t = tid; t < SS * 2016; t += 256) {
        const int s = t / 2016;
        int rem = t % 2016;
        int i = 0;
        while (rem >= 63 - i) { rem -= 63 - i; ++i; }
        const int j = i + 1 + rem;
        float dsum = 0.f;
#pragma unroll
        for (int d = 0; d < DD; ++d) {
            const int ch = s * DD + d;
            dsum += fabsf(centB[ch * NSEGC + i] - centB[ch * NSEGC + j]);
        }
        const float cd = dsum * (1.f / DD);
        const float r = fmaxf(MARGINF - cd, 0.f);
        acc += r * r;
    }
    for (int o = 32; o > 0; o >>= 1) acc += __shfl_down(acc, o, 64);
    if ((tid & 63) == 0) red[tid >> 6] = acc;
    __syncthreads();
    if (tid == 0)
        g_push[b] = (red[0] + red[1] + red[2] + red[3]) * (1.0f / (SS * 2016));
}

// ---------------- kernel C: pull loss ----------------
__global__ __launch_bounds__(BLK) void k_pull(const float* __restrict__ preds,
                                              const int* __restrict__ labels,
                                              const float* __restrict__ g_cent, // [B][NSEG][CH]
                                              float* __restrict__ g_pull)       // [B]
{
    __shared__ float centL[NSEGC * 33];   // [seg][ch], stride 33 -> bank spread
    __shared__ float red[4];
    const int b    = blockIdx.x / NCHUNK;
    const int base = (blockIdx.x % NCHUNK) * CHUNK;
    const int tid  = threadIdx.x;

    for (int i = tid; i < NSEGC * CH; i += BLK) {
        const int seg = i >> 5, ch = i & 31;
        centL[seg * 33 + ch] = g_cent[(size_t)b * NSEGC * CH + i];
    }
    const int4 lv = ((const int4*)(labels + (size_t)b * PP + base))[tid];
    const int c0 = lv.x * 33, c1 = lv.y * 33, c2 = lv.z * 33, c3 = lv.w * 33;
    __syncthreads();

    const float* pb = preds + (size_t)b * CH * PP + base;
    float total = 0.f;
#pragma unroll
    for (int s = 0; s < SS; ++s) {
        float a0 = 0.f, a1 = 0.f, a2 = 0.f, a3 = 0.f;
#pragma unroll 8
        for (int d = 0; d < DD; ++d) {
            const int ch = s * DD + d;
            const float4 v = ((const float4*)(pb + (size_t)ch * PP))[tid];
            a0 += fabsf(v.x - centL[c0 + ch]);
            a1 += fabsf(v.y - centL[c1 + ch]);
            a2 += fabsf(v.z - centL[c2 + ch]);
            a3 += fabsf(v.w - centL[c3 + ch]);
        }
        float q;
        q = a0 * (1.f / DD); total += q * q;
        q = a1 * (1.f / DD); total += q * q;
        q = a2 * (1.f / DD); total += q * q;
        q = a3 * (1.f / DD); total += q * q;
    }
    for (int o = 32; o > 0; o >>= 1) total += __shfl_down(total, o, 64);
    if ((tid & 63) == 0) red[tid >> 6] = total;
    __syncthreads();
    if (tid == 0)
        atomicAdd(&g_pull[b], red[0] + red[1] + red[2] + red[3]);
}

// ---------------- kernel D: finalize ----------------
__global__ void k_final(const float* __restrict__ g_push,
                        const float* __restrict__ g_pull,
                        float* __restrict__ out)
{
    if (threadIdx.x == 0 && blockIdx.x == 0) {
        float acc = 0.f;
        for (int b = 0; b < BB; ++b)
            acc += g_push[b] + 0.1f * (g_pull[b] * (1.0f / (SS * PP)));
        out[0] = acc * (1.0f / BB);
    }
}

extern "C" void kernel_launch(void* const* d_in, const int* in_sizes, int n_in,
                              void* d_out, int out_size, void* d_ws, size_t ws_size,
                              hipStream_t stream) {
    const float* preds  = (const float*)d_in[0];
    const int*   labels = (const int*)d_in[1];

    float* ws       = (float*)d_ws;
    float* g_sums   = ws;                              // B*CH*NSEG = 8192
    float* g_counts = g_sums + BB * CH * NSEGC;        // B*NSEG    = 256
    float* g_pull   = g_counts + BB * NSEGC;           // B         = 4
    float* g_push   = g_pull + BB;                     // B         = 4
    float* g_cent   = g_push + BB;                     // B*NSEG*CH = 8192

    // zero the accumulated region (sums, counts, pull) every call — replays must not accumulate
    hipMemsetAsync(d_ws, 0, (size_t)(BB * CH * NSEGC + BB * NSEGC + BB) * sizeof(float), stream);

    k_sums <<<BB * NCHUNK, BLK, 0, stream>>>(preds, labels, g_sums, g_counts);
    k_push <<<BB, 256, 0, stream>>>(g_sums, g_counts, g_cent, g_push);
    k_pull <<<BB * NCHUNK, BLK, 0, stream>>>(preds, labels, g_cent, g_pull);
    k_final<<<1, 64, 0, stream>>>(g_push, g_pull, (float*)d_out);
}

// Round 3
// 92.076 us; speedup vs baseline: 2.5813x; 2.5813x over previous
//
#include <hip/hip_runtime.h>
#include <hip/hip_bf16.h>

#define BB 4
#define SS 2
#define DD 16
#define CH 32          // S*D
#define PP (512*512)   // pixels per item
#define NSEGC 64
#define MARGINF 0.25f
#define CHUNK 1024              // pixels per block
#define NCHUNK (PP/CHUNK)       // 256 chunks per batch -> grid 1024

typedef __attribute__((ext_vector_type(4))) float  f32x4;
typedef __attribute__((ext_vector_type(8))) short  short8;

__device__ inline short f2bf(float x) {
    union { __hip_bfloat16 h; short s; } u;
    u.h = __float2bfloat16(x);   // RNE
    return u.s;
}

// ---------------- kernel A: segment sums + counts via one-hot MFMA ----------------
// sums[seg][ch] = sum_p onehot[seg][p] * t[p][ch]  (M=64 -> 4 tiles, N=32 -> 2 tiles, K chunked by 32)
__global__ __launch_bounds__(256) void k_sums(const float* __restrict__ preds,
                                              const int* __restrict__ labels,
                                              float* __restrict__ g_sums,    // [B][CH][NSEG]
                                              float* __restrict__ g_counts)  // [B][NSEG]
{
    __shared__ int   labs[CHUNK];
    __shared__ float buf[4][CH][68];     // per-wave result, [ch][seg(64)+pad]
    __shared__ float cbuf[4][NSEGC];

    const int b    = blockIdx.x / NCHUNK;
    const int base = (blockIdx.x % NCHUNK) * CHUNK;
    const int tid  = threadIdx.x;
    const int w    = tid >> 6;           // wave 0..3
    const int l    = tid & 63;
    const int lm   = l & 15;             // A-row / B-col / D-col
    const int lk   = l >> 4;             // k-group

    ((int4*)labs)[tid] = ((const int4*)(labels + (size_t)b * PP + base))[tid];

    f32x4 acc[4][2];
    f32x4 accc[4];
#pragma unroll
    for (int mt = 0; mt < 4; ++mt) {
        accc[mt] = f32x4{0.f, 0.f, 0.f, 0.f};
#pragma unroll
        for (int nt = 0; nt < 2; ++nt) acc[mt][nt] = f32x4{0.f, 0.f, 0.f, 0.f};
    }
    short8 ones;
#pragma unroll
    for (int j = 0; j < 8; ++j) ones[j] = (short)0x3F80;  // bf16 1.0

    __syncthreads();

    const float* pb = preds + (size_t)b * CH * PP + base;

    // each wave owns 8 K-chunks of 32 pixels (wave w -> pixels [w*256, w*256+256))
#pragma unroll 2
    for (int c = 0; c < 8; ++c) {
        const int kbase = (w * 8 + c) * 32 + lk * 8;   // this lane's 8 pixels (within block)
        const int4 L0 = *(const int4*)&labs[kbase];
        const int4 L1 = *(const int4*)&labs[kbase + 4];
        const int labv[8] = {L0.x, L0.y, L0.z, L0.w, L1.x, L1.y, L1.z, L1.w};

        // one-hot A fragments: af[mt][j] = (label(pixel) == mt*16+lm) ? 1.0bf : 0
        short8 af[4];
#pragma unroll
        for (int mt = 0; mt < 4; ++mt) {
            const int target = mt * 16 + lm;
#pragma unroll
            for (int j = 0; j < 8; ++j)
                af[mt][j] = (labv[j] == target) ? (short)0x3F80 : (short)0;
        }

        // B fragments: channel nt*16+lm, this lane's 8 pixels; f32 -> bf16
#pragma unroll
        for (int nt = 0; nt < 2; ++nt) {
            const float* src = pb + (size_t)(nt * 16 + lm) * PP + kbase;
            const float4 v0 = ((const float4*)src)[0];
            const float4 v1 = ((const float4*)src)[1];
            short8 bf;
            bf[0] = f2bf(v0.x); bf[1] = f2bf(v0.y); bf[2] = f2bf(v0.z); bf[3] = f2bf(v0.w);
            bf[4] = f2bf(v1.x); bf[5] = f2bf(v1.y); bf[6] = f2bf(v1.z); bf[7] = f2bf(v1.w);
#pragma unroll
            for (int mt = 0; mt < 4; ++mt)
                acc[mt][nt] = __builtin_amdgcn_mfma_f32_16x16x32_bf16(af[mt], bf, acc[mt][nt], 0, 0, 0);
        }
        // counts: row-sum of one-hot via B = ones
#pragma unroll
        for (int mt = 0; mt < 4; ++mt)
            accc[mt] = __builtin_amdgcn_mfma_f32_16x16x32_bf16(af[mt], ones, accc[mt], 0, 0, 0);
    }

    // D layout: col = lane&15, row = (lane>>4)*4 + reg  (m89-verified)
#pragma unroll
    for (int mt = 0; mt < 4; ++mt) {
#pragma unroll
        for (int nt = 0; nt < 2; ++nt)
            *(f32x4*)&buf[w][nt * 16 + lm][mt * 16 + lk * 4] = acc[mt][nt];
        if (lm == 0)
            *(f32x4*)&cbuf[w][mt * 16 + lk * 4] = accc[mt];
    }
    __syncthreads();

    for (int i = tid; i < CH * NSEGC; i += 256) {
        const int col = i >> 6, row = i & 63;   // i = ch*64 + seg
        const float s = buf[0][col][row] + buf[1][col][row] + buf[2][col][row] + buf[3][col][row];
        atomicAdd(&g_sums[(size_t)b * CH * NSEGC + i], s);
    }
    if (tid < NSEGC)
        atomicAdd(&g_counts[b * NSEGC + tid],
                  cbuf[0][tid] + cbuf[1][tid] + cbuf[2][tid] + cbuf[3][tid]);
}

// ---------------- kernel B: centroids + push loss ----------------
__global__ __launch_bounds__(256) void k_push(const float* __restrict__ g_sums,
                                              const float* __restrict__ g_counts,
                                              float* __restrict__ g_cent,   // [B][NSEG][CH]
                                              float* __restrict__ g_push)   // [B]
{
    __shared__ float centB[CH * NSEGC];  // [ch][seg]
    __shared__ float red[4];
    const int b = blockIdx.x;
    const int tid = threadIdx.x;

    for (int i = tid; i < CH * NSEGC; i += 256) {
        const int ch = i >> 6, seg = i & 63;
        const float cnt = fmaxf(g_counts[b * NSEGC + seg], 1.0f);
        const float c = g_sums[(size_t)b * CH * NSEGC + i] / cnt;
        centB[i] = c;
        g_cent[(size_t)b * NSEGC * CH + seg * CH + ch] = c;
    }
    __syncthreads();

    float acc = 0.f;
    for (int t = tid; t < SS * 2016; t += 256) {
        const int s = t / 2016;
        int rem = t % 2016;
        int i = 0;
        while (rem >= 63 - i) { rem -= 63 - i; ++i; }
        const int j = i + 1 + rem;
        float dsum = 0.f;
#pragma unroll
        for (int d = 0; d < DD; ++d) {
            const int ch = s * DD + d;
            dsum += fabsf(centB[ch * NSEGC + i] - centB[ch * NSEGC + j]);
        }
        const float cd = dsum * (1.f / DD);
        const float r = fmaxf(MARGINF - cd, 0.f);
        acc += r * r;
    }
    for (int o = 32; o > 0; o >>= 1) acc += __shfl_down(acc, o, 64);
    if ((tid & 63) == 0) red[tid >> 6] = acc;
    __syncthreads();
    if (tid == 0)
        g_push[b] = (red[0] + red[1] + red[2] + red[3]) * (1.0f / (SS * 2016));
}

// ---------------- kernel C: pull loss ----------------
__global__ __launch_bounds__(256) void k_pull(const float* __restrict__ preds,
                                              const int* __restrict__ labels,
                                              const float* __restrict__ g_cent, // [B][NSEG][CH]
                                              float* __restrict__ g_pull)       // [B]
{
    __shared__ float centL[NSEGC * 33];   // [seg][ch], stride 33 -> bank spread
    __shared__ float red[4];
    const int b    = blockIdx.x / NCHUNK;
    const int base = (blockIdx.x % NCHUNK) * CHUNK;
    const int tid  = threadIdx.x;

    for (int i = tid; i < NSEGC * CH; i += 256) {
        const int seg = i >> 5, ch = i & 31;
        centL[seg * 33 + ch] = g_cent[(size_t)b * NSEGC * CH + i];
    }
    const int4 lv = ((const int4*)(labels + (size_t)b * PP + base))[tid];
    const int c0 = lv.x * 33, c1 = lv.y * 33, c2 = lv.z * 33, c3 = lv.w * 33;
    __syncthreads();

    const float* pb = preds + (size_t)b * CH * PP + base;
    float total = 0.f;
#pragma unroll
    for (int s = 0; s < SS; ++s) {
        float a0 = 0.f, a1 = 0.f, a2 = 0.f, a3 = 0.f;
#pragma unroll 8
        for (int d = 0; d < DD; ++d) {
            const int ch = s * DD + d;
            const float4 v = ((const float4*)(pb + (size_t)ch * PP))[tid];
            a0 += fabsf(v.x - centL[c0 + ch]);
            a1 += fabsf(v.y - centL[c1 + ch]);
            a2 += fabsf(v.z - centL[c2 + ch]);
            a3 += fabsf(v.w - centL[c3 + ch]);
        }
        float q;
        q = a0 * (1.f / DD); total += q * q;
        q = a1 * (1.f / DD); total += q * q;
        q = a2 * (1.f / DD); total += q * q;
        q = a3 * (1.f / DD); total += q * q;
    }
    for (int o = 32; o > 0; o >>= 1) total += __shfl_down(total, o, 64);
    if ((tid & 63) == 0) red[tid >> 6] = total;
    __syncthreads();
    if (tid == 0)
        atomicAdd(&g_pull[b], red[0] + red[1] + red[2] + red[3]);
}

// ---------------- kernel D: finalize ----------------
__global__ void k_final(const float* __restrict__ g_push,
                        const float* __restrict__ g_pull,
                        float* __restrict__ out)
{
    if (threadIdx.x == 0 && blockIdx.x == 0) {
        float acc = 0.f;
        for (int b = 0; b < BB; ++b)
            acc += g_push[b] + 0.1f * (g_pull[b] * (1.0f / (SS * PP)));
        out[0] = acc * (1.0f / BB);
    }
}

extern "C" void kernel_launch(void* const* d_in, const int* in_sizes, int n_in,
                              void* d_out, int out_size, void* d_ws, size_t ws_size,
                              hipStream_t stream) {
    const float* preds  = (const float*)d_in[0];
    const int*   labels = (const int*)d_in[1];

    float* ws       = (float*)d_ws;
    float* g_sums   = ws;                              // B*CH*NSEG = 8192
    float* g_counts = g_sums + BB * CH * NSEGC;        // B*NSEG    = 256
    float* g_pull   = g_counts + BB * NSEGC;           // B         = 4
    float* g_push   = g_pull + BB;                     // B         = 4
    float* g_cent   = g_push + BB;                     // B*NSEG*CH = 8192

    // zero the accumulated region (sums, counts, pull) every call — replays must not accumulate
    hipMemsetAsync(d_ws, 0, (size_t)(BB * CH * NSEGC + BB * NSEGC + BB) * sizeof(float), stream);

    k_sums <<<BB * NCHUNK, 256, 0, stream>>>(preds, labels, g_sums, g_counts);
    k_push <<<BB, 256, 0, stream>>>(g_sums, g_counts, g_cent, g_push);
    k_pull <<<BB * NCHUNK, 256, 0, stream>>>(preds, labels, g_cent, g_pull);
    k_final<<<1, 64, 0, stream>>>(g_push, g_pull, (float*)d_out);
}